// Round 12
// baseline (113.192 us; speedup 1.0000x reference)
//
#include <hip/hip_runtime.h>
#include <stdint.h>

#define NB 2
#define NC 34
#define HH 512
#define WW 1024
#define HWW (HH*WW)
#define KK 200
#define MCAP 4096
#define VBIN 4096
#define SLOTS 256
#define NTILE 256
#define CAP2 32768
#define SEGB (NB*HWW/1024)   // 1024 seg blocks (4 px/thread, 256 thr)
#define NMSB (NB*NTILE)      // 512 nms tile blocks
#define STRIP 4096           // k_sums pixels per block

// NMS tiling
#define TW 128
#define TH 16
#define HALO 3

// ========== fused: per-pixel online-softmax argmax/stat  +  NMS tiles ==========
__global__ void __launch_bounds__(256)
k_seg_nms(const float* __restrict__ logits, const float* __restrict__ cmap,
          float* __restrict__ segs_out, float* __restrict__ scomb,
          unsigned char* __restrict__ seg8,
          uint64_t* __restrict__ cand2, uint32_t* __restrict__ cnt,
          uint32_t* __restrict__ ghist, int use_stats) {
    int bid = blockIdx.x;
    int tid = threadIdx.x;

    if (bid < SEGB) {
        int t = bid * 256 + tid;
        int p = t * 4;
        int b = p / HWW, r = p - b * HWW;
        const float* base = logits + (size_t)b * NC * HWW + r;
        float4 m = make_float4(-3e38f, -3e38f, -3e38f, -3e38f);
        float4 s = make_float4(0.f, 0.f, 0.f, 0.f);
        int ax = 0, ay = 0, az = 0, aw = 0;
#pragma unroll
        for (int c = 0; c < NC; ++c) {
            float4 v = *(const float4*)(base + (size_t)c * HWW);
            if (v.x > m.x) { s.x = s.x * __expf(m.x - v.x) + 1.f; m.x = v.x; ax = c; }
            else            s.x += __expf(v.x - m.x);
            if (v.y > m.y) { s.y = s.y * __expf(m.y - v.y) + 1.f; m.y = v.y; ay = c; }
            else            s.y += __expf(v.y - m.y);
            if (v.z > m.z) { s.z = s.z * __expf(m.z - v.z) + 1.f; m.z = v.z; az = c; }
            else            s.z += __expf(v.z - m.z);
            if (v.w > m.w) { s.w = s.w * __expf(m.w - v.w) + 1.f; m.w = v.w; aw = c; }
            else            s.w += __expf(v.w - m.w);
        }
        *(float4*)(segs_out + p) = make_float4((float)ax, (float)ay, (float)az, (float)aw);
        *(uchar4*)(seg8 + p) = make_uchar4((unsigned char)ax, (unsigned char)ay,
                                           (unsigned char)az, (unsigned char)aw);
        if (use_stats) {   // pr(class c) = exp(logit_c - scomb)
            *(float4*)(scomb + p) = make_float4(m.x + __logf(s.x), m.y + __logf(s.y),
                                                m.z + __logf(s.z), m.w + __logf(s.w));
        }
        return;
    }

    // ---------------- NMS tile: direct dense write + global histogram ----------------
    __shared__ float sIn[TH + 2 * HALO][TW + 2 * HALO];   // 22 x 134
    __shared__ float sH[TH + 2 * HALO][TW];               // 22 x 128
    __shared__ uint64_t lc[SLOTS];
    __shared__ uint32_t lcnt, gbase;
    int t2 = bid - SEGB;
    int bx = t2 & (WW / TW - 1);
    int by = (t2 >> 3) & (HH / TH - 1);
    int b = t2 >> 8;
    const float* bb = cmap + (size_t)b * HWW;
    if (tid == 0) lcnt = 0u;

    const int LW = TW + 2 * HALO;
    const int LH = TH + 2 * HALO;
    for (int idx = tid; idx < LW * LH; idx += 256) {
        int r = idx / LW, c = idx - r * LW;
        int gh = by * TH + r - HALO;
        int gw = bx * TW + c - HALO;
        float v = -3e38f;
        if (gh >= 0 && gh < HH && gw >= 0 && gw < WW) v = bb[gh * WW + gw];
        sIn[r][c] = v;
    }
    __syncthreads();
    for (int idx = tid; idx < LH * TW; idx += 256) {
        int r = idx / TW, c = idx - r * TW;
        float m = fmaxf(fmaxf(fmaxf(sIn[r][c], sIn[r][c + 1]),
                              fmaxf(sIn[r][c + 2], sIn[r][c + 3])),
                        fmaxf(fmaxf(sIn[r][c + 4], sIn[r][c + 5]), sIn[r][c + 6]));
        sH[r][c] = m;
    }
    __syncthreads();
    for (int idx = tid; idx < TH * TW; idx += 256) {
        int r = idx >> 7, c = idx & (TW - 1);
        float cv = sIn[r + HALO][c + HALO];
        float m = fmaxf(fmaxf(fmaxf(sH[r][c], sH[r + 1][c]),
                              fmaxf(sH[r + 2][c], sH[r + 3][c])),
                        fmaxf(fmaxf(sH[r + 4][c], sH[r + 5][c]), sH[r + 6][c]));
        if (m > 0.1f && cv == m) {
            int gh = by * TH + r;
            int gw = bx * TW + c;
            uint32_t rr = (uint32_t)(gh * WW + gw);
            uint32_t pos = atomicAdd(&lcnt, 1u);
            if (pos < SLOTS) {
                lc[pos] = ((uint64_t)__float_as_uint(cv) << 32) |
                          (uint64_t)(0xFFFFFFFFu - rr);
                int bin = (int)(cv * (float)VBIN);
                bin = bin < 0 ? 0 : (bin > VBIN - 1 ? VBIN - 1 : bin);
                atomicAdd(&ghist[b * VBIN + bin], 1u);   // spread bins: low contention
            }
        }
    }
    __syncthreads();
    uint32_t n = lcnt;
    if (n > SLOTS) n = SLOTS;
    if (tid == 0 && n) gbase = atomicAdd(&cnt[b], n);   // ONE global reserve per block
    __syncthreads();
    for (uint32_t i = tid; i < n; i += 256) {
        uint32_t pos = gbase + i;
        if (pos < CAP2) cand2[(size_t)b * CAP2 + pos] = lc[i];
    }
}

// ==== exact top-K from prebuilt hist + dense candidates + exact rank ====
__global__ void __launch_bounds__(1024) k_topk2(const uint64_t* __restrict__ cand2,
                                                const uint32_t* __restrict__ cnt,
                                                const uint32_t* __restrict__ ghist,
                                                float* __restrict__ probs_out,
                                                float* __restrict__ cxy) {
    int b = blockIdx.x;
    int tid = threadIdx.x;
    int lane = tid & 63, wv = tid >> 6;
    __shared__ uint32_t hist[VBIN];
    __shared__ uint32_t part[1024];
    __shared__ uint32_t wsum[16];
    __shared__ uint64_t lkey[MCAP];
    __shared__ uint32_t lM;
    __shared__ int sBstar;

    if (tid < KK) {
        probs_out[b * KK + tid] = 0.f;
        cxy[(b * KK + tid) * 2]     = 1e19f;
        cxy[(b * KK + tid) * 2 + 1] = 1e19f;
    }
    if (tid == 0) { lM = 0u; sBstar = 0; }
    for (int i = tid; i < VBIN; i += 1024) hist[i] = ghist[b * VBIN + i];
    uint32_t N = cnt[b];
    if (N > CAP2) N = CAP2;
    const uint64_t* cb = cand2 + (size_t)b * CAP2;
    __syncthreads();

    // chunk sums in DESCENDING value order, then two-level inclusive scan
    int base = VBIN - 4 * (tid + 1);
    uint32_t s = hist[base] + hist[base + 1] + hist[base + 2] + hist[base + 3];
    uint32_t sc = s;
#pragma unroll
    for (int off = 1; off < 64; off <<= 1) {
        uint32_t nv = __shfl_up(sc, off, 64);
        if (lane >= off) sc += nv;
    }
    if (lane == 63) wsum[wv] = sc;
    __syncthreads();
    if (wv == 0) {
        uint32_t t0 = (lane < 16) ? wsum[lane] : 0u;
#pragma unroll
        for (int off = 1; off < 16; off <<= 1) {
            uint32_t nv = __shfl_up(t0, off, 64);
            if (lane >= off) t0 += nv;
        }
        if (lane < 16) wsum[lane] = t0;
    }
    __syncthreads();
    uint32_t inc = sc + (wv > 0 ? wsum[wv - 1] : 0u);
    part[tid] = inc;
    __syncthreads();
    {
        uint32_t Pt = part[tid];
        uint32_t Pp = (tid > 0) ? part[tid - 1] : 0u;
        if (Pt >= KK && Pp < KK) {
            uint32_t cum = Pp;
            int bs = base;
            for (int j = base + 3; j >= base; --j) {
                cum += hist[j];
                if (cum >= KK) { bs = j; break; }
            }
            sBstar = bs;
        }
    }
    __syncthreads();
    int bstar = sBstar;   // 0 when total candidates <= KK -> collect all

    for (uint32_t i = tid; i < N; i += 1024) {
        uint64_t kk = cb[i];
        float v = __uint_as_float((uint32_t)(kk >> 32));
        int bin = (int)(v * (float)VBIN);
        bin = bin < 0 ? 0 : (bin > VBIN - 1 ? VBIN - 1 : bin);
        if (bin >= bstar) {
            uint32_t pos = atomicAdd(&lM, 1u);
            if (pos < MCAP) lkey[pos] = kk;
        }
    }
    __syncthreads();
    uint32_t M = lM;
    if (M > MCAP) M = MCAP;
    for (uint32_t i = tid; i < M; i += 1024) {
        uint64_t kk = lkey[i];
        uint32_t rank = 0;
        for (uint32_t j = 0; j < M; ++j) rank += (lkey[j] > kk) ? 1u : 0u;
        if (rank < KK) {
            uint32_t bits = (uint32_t)(kk >> 32);
            uint32_t idx = 0xFFFFFFFFu - (uint32_t)(kk & 0xFFFFFFFFull);
            probs_out[b * KK + rank] = __uint_as_float(bits);
            cxy[(b * KK + rank) * 2]     = (float)(idx % WW);
            cxy[(b * KK + rank) * 2 + 1] = (float)(idx / WW);
        }
    }
}

// ------------- closest-center argmin with EXACT per-tile pruning + counts hist
__global__ void __launch_bounds__(256) k_assign(const float* __restrict__ reg,
                                                const float* __restrict__ cxy,
                                                const unsigned char* __restrict__ seg8,
                                                float* __restrict__ closest_out,
                                                uint16_t* __restrict__ aux,
                                                uint32_t* __restrict__ counts) {
    __shared__ float2 cc[KK];
    __shared__ float4 ccs[KK];
    __shared__ float sred[4][4];
    __shared__ uint32_t wcnt[4];
    __shared__ float stau2;
    __shared__ uint32_t sS;

    int t = blockIdx.x;
    int tx = t & 63;
    int ty = (t >> 6) & 31;
    int b = t >> 11;
    int tid = threadIdx.x;
    int lane = tid & 63, wv = tid >> 6;
    int w = tx * 16 + (tid & 15);
    int h = ty * 16 + (tid >> 4);
    int r = h * WW + w;
    int p = b * HWW + r;

    if (tid < KK) cc[tid] = ((const float2*)cxy)[b * KK + tid];
    __syncthreads();

    float rx = reg[(size_t)b * 2 * HWW + r];
    float ry = reg[(size_t)b * 2 * HWW + HWW + r];
    float px = (float)(w + 1) - rx;
    float py = (float)(h + 1) - ry;

    float mnx = px, mxx = px, mny = py, mxy = py;
#pragma unroll
    for (int off = 1; off < 64; off <<= 1) {
        mnx = fminf(mnx, __shfl_xor(mnx, off, 64));
        mxx = fmaxf(mxx, __shfl_xor(mxx, off, 64));
        mny = fminf(mny, __shfl_xor(mny, off, 64));
        mxy = fmaxf(mxy, __shfl_xor(mxy, off, 64));
    }
    if (lane == 0) { sred[0][wv] = mnx; sred[1][wv] = mxx; sred[2][wv] = mny; sred[3][wv] = mxy; }
    __syncthreads();
    float xmin = fminf(fminf(sred[0][0], sred[0][1]), fminf(sred[0][2], sred[0][3]));
    float xmax = fmaxf(fmaxf(sred[1][0], sred[1][1]), fmaxf(sred[1][2], sred[1][3]));
    float ymin = fminf(fminf(sred[2][0], sred[2][1]), fminf(sred[2][2], sred[2][3]));
    float ymax = fmaxf(fmaxf(sred[3][0], sred[3][1]), fmaxf(sred[3][2], sred[3][3]));

    float2 c0 = cc[tid < KK ? tid : 0];
    float mdx = fmaxf(fmaxf(xmin - c0.x, c0.x - xmax), 0.f);
    float mdy = fmaxf(fmaxf(ymin - c0.y, c0.y - ymax), 0.f);
    float mind2 = mdx * mdx + mdy * mdy;
    float Mdx = fmaxf(c0.x - xmin, xmax - c0.x);
    float Mdy = fmaxf(c0.y - ymin, ymax - c0.y);
    float maxd2 = Mdx * Mdx + Mdy * Mdy;

    float v = (tid < KK) ? maxd2 : 3.0e38f;
#pragma unroll
    for (int off = 1; off < 64; off <<= 1) v = fminf(v, __shfl_xor(v, off, 64));
    if (lane == 0) sred[0][wv] = v;
    __syncthreads();
    if (tid == 0) {
        float mm = fminf(fminf(sred[0][0], sred[0][1]), fminf(sred[0][2], sred[0][3]));
        float tau = __builtin_sqrtf(mm) + 1.0f;
        stau2 = tau * tau;
    }
    __syncthreads();

    bool flag = (tid < KK) && (mind2 <= stau2);
    uint64_t mask = __ballot(flag);
    uint32_t myoff = (uint32_t)__popcll(mask & ((1ull << lane) - 1ull));
    if (lane == 0) wcnt[wv] = (uint32_t)__popcll(mask);
    __syncthreads();
    uint32_t pre = 0;
    for (int i = 0; i < wv; ++i) pre += wcnt[i];
    if (flag) ccs[pre + myoff] = make_float4(c0.x, c0.y, (float)tid, 0.f);
    if (tid == 0) sS = wcnt[0] + wcnt[1] + wcnt[2] + wcnt[3];
    __syncthreads();
    uint32_t S = sS;

    float best = __builtin_inff();
    float bkf = 0.f;
    for (uint32_t s = 0; s < S; ++s) {
        float4 c = ccs[s];
        float dx = __fsub_rn(px, c.x);
        float dy = __fsub_rn(py, c.y);
        float d2 = __fadd_rn(__fmul_rn(dx, dx), __fmul_rn(dy, dy));  // no fma, match ref
        if (d2 < best) { best = d2; bkf = c.z; }   // first-occurrence (asc k order)
    }
    int bk = (int)bkf;
    closest_out[p] = bkf + 1.0f;
    int seg = (int)seg8[p];
    aux[p] = (uint16_t)(((bk + 1) << 6) | seg);
    if (seg >= 24 && seg <= 33) {
        atomicAdd(&counts[(b * (KK + 1) + (bk + 1)) * NC + seg], 1u);
    }
}

// ---- per-instance sums over a 4096-px strip; ic recomputed per block from counts
// ---- first strip block of each batch also emits o_ic / o_np / o_va  (was k_inst)
template <int USE_STATS>
__global__ void __launch_bounds__(256) k_sums(const float* __restrict__ logits,
                                              const uint16_t* __restrict__ aux,
                                              const float* __restrict__ scomb,
                                              const uint32_t* __restrict__ counts,
                                              const float* __restrict__ probs_out,
                                              float* __restrict__ sums,
                                              float* __restrict__ ic_out,
                                              float* __restrict__ np_out,
                                              float* __restrict__ va_out) {
    __shared__ int ic_l[KK];
    __shared__ float psum[KK + 1];
    int tid = threadIdx.x;
    int sblk = blockIdx.x;
    int b = sblk / (HWW / STRIP);
    int p0 = sblk * STRIP;

    if (tid < KK) {   // recompute majority class (identical first-occurrence argmax)
        const uint32_t* row = counts + (size_t)(b * (KK + 1) + (tid + 1)) * NC;
        uint32_t n = 0, mx = 0;
        int am = 0;
#pragma unroll
        for (int c = 0; c < NC; ++c) {
            uint32_t x = row[c];
            n += x;
            if (x > mx) { mx = x; am = c; }
        }
        ic_l[tid] = am;
        if ((sblk % (HWW / STRIP)) == 0) {   // once per batch: k_inst outputs
            ic_out[b * KK + tid] = (float)am;
            np_out[b * KK + tid] = (float)n;
            va_out[b * KK + tid] =
                (n > 0u && probs_out[b * KK + tid] > 0.f) ? 1.f : 0.f;
        }
    }
    if (tid < KK + 1) psum[tid] = 0.f;
    __syncthreads();

#pragma unroll 1
    for (int ch = 0; ch < STRIP / 512; ++ch) {
        int p = p0 + ch * 512 + tid * 2;
        int r = p - b * HWW;
        uint32_t a2 = *(const uint32_t*)(aux + p);
        int seg0 = (int)(a2 & 63u), seg1 = (int)((a2 >> 16) & 63u);
        bool th0 = (seg0 >= 24) & (seg0 <= 33);
        bool th1 = (seg1 >= 24) & (seg1 <= 33);
        float2 sc = make_float2(0.f, 0.f);
        if (USE_STATS && (th0 || th1)) sc = *(const float2*)(scomb + p);
        const float* base = logits + (size_t)b * NC * HWW + r;
#pragma unroll
        for (int j = 0; j < 2; ++j) {
            bool th = j ? th1 : th0;
            if (th) {
                uint32_t pk = (a2 >> (16 * j)) & 0xFFFFu;
                int cl = (int)(pk >> 6);
                int ic = ic_l[cl - 1];
                float pr;
                if (USE_STATS) {
                    float lv = base[(size_t)ic * HWW + j];
                    pr = __expf(lv - (j ? sc.y : sc.x));
                } else {
                    float vmax = -3e38f, lv = 0.f, s = 0.f;
                    float vv[NC];
#pragma unroll
                    for (int c = 0; c < NC; ++c) {
                        vv[c] = base[(size_t)c * HWW + j];
                        vmax = fmaxf(vmax, vv[c]);
                        if (c == ic) lv = vv[c];
                    }
#pragma unroll
                    for (int c = 0; c < NC; ++c) s += __expf(vv[c] - vmax);
                    pr = __expf(lv - vmax) / s;
                }
                atomicAdd(&psum[cl], pr);
            }
        }
    }
    __syncthreads();
    if (tid < KK + 1) {
        float x = psum[tid];
        if (x != 0.f) atomicAdd(&sums[b * (KK + 1) + tid], x);
    }
}

// ---------------------------------------- final seg_prob
__global__ void __launch_bounds__(256) k_segprob(const float* __restrict__ sums,
                                                 const float* __restrict__ np_out,
                                                 float* __restrict__ sp_out) {
    int t = blockIdx.x * 256 + threadIdx.x;
    if (t >= NB * KK) return;
    int b = t / KK, k = t - b * KK;
    float n = np_out[t];
    float s = sums[b * (KK + 1) + k + 1];
    sp_out[t] = (n > 0.f) ? (s / n) : 0.f;
}

extern "C" void kernel_launch(void* const* d_in, const int* in_sizes, int n_in,
                              void* d_out, int out_size, void* d_ws, size_t ws_size,
                              hipStream_t stream) {
    const float* logits = (const float*)d_in[0];
    const float* cmap   = (const float*)d_in[1];
    const float* reg    = (const float*)d_in[2];
    float* out = (float*)d_out;
    float* o_ic   = out;
    float* o_prob = out + NB * KK;
    float* o_sp   = out + 2 * NB * KK;
    float* o_np   = out + 3 * NB * KK;
    float* o_va   = out + 4 * NB * KK;
    float* o_segs = out + 5 * NB * KK;
    float* o_clo  = out + 5 * NB * KK + NB * HWW;

    char* w = (char*)d_ws;
    size_t off = 0;
    auto alloc = [&](size_t bytes) {
        off = (off + 15) & ~((size_t)15);
        void* p = w + off;
        off += bytes;
        return p;
    };
    // zero-region: [cnt pad4][ghist][counts][sums]  -> one memset
    uint32_t* zbase  = (uint32_t*)alloc(sizeof(uint32_t) * (4 + NB * VBIN + NB * (KK + 1) * NC + NB * (KK + 1)));
    uint32_t* cnt    = zbase;
    uint32_t* ghist  = zbase + 4;
    uint32_t* counts = ghist + NB * VBIN;
    float*    sums   = (float*)(counts + NB * (KK + 1) * NC);
    size_t zbytes = sizeof(uint32_t) * (4 + NB * VBIN + NB * (KK + 1) * NC + NB * (KK + 1));

    uint64_t* cand2  = (uint64_t*)alloc(sizeof(uint64_t) * NB * CAP2);
    float* cxy       = (float*)alloc(sizeof(float) * NB * KK * 2);
    unsigned char* seg8 = (unsigned char*)alloc(sizeof(unsigned char) * NB * HWW);
    uint16_t* aux    = (uint16_t*)alloc(sizeof(uint16_t) * NB * HWW);
    size_t base_need = (off + 15) & ~((size_t)15);
    float* scomb = (float*)(w + base_need);
    int use_stats = (base_need + sizeof(float) * (size_t)NB * HWW) <= ws_size ? 1 : 0;

    hipMemsetAsync(zbase, 0, zbytes, stream);
    k_seg_nms<<<SEGB + NMSB, 256, 0, stream>>>(logits, cmap, o_segs, scomb, seg8,
                                               cand2, cnt, ghist, use_stats);
    k_topk2<<<NB, 1024, 0, stream>>>(cand2, cnt, ghist, o_prob, cxy);
    k_assign<<<NB * 2048, 256, 0, stream>>>(reg, cxy, seg8, o_clo, aux, counts);
    if (use_stats)
        k_sums<1><<<NB * HWW / STRIP, 256, 0, stream>>>(logits, aux, scomb, counts,
                                                        o_prob, sums, o_ic, o_np, o_va);
    else
        k_sums<0><<<NB * HWW / STRIP, 256, 0, stream>>>(logits, aux, scomb, counts,
                                                        o_prob, sums, o_ic, o_np, o_va);
    k_segprob<<<(NB * KK + 255) / 256, 256, 0, stream>>>(sums, o_np, o_sp);
}

// Round 13
// 110.921 us; speedup vs baseline: 1.0205x; 1.0205x over previous
//
#include <hip/hip_runtime.h>
#include <stdint.h>

#define NB 2
#define NC 34
#define HH 512
#define WW 1024
#define HWW (HH*WW)
#define KK 200
#define MCAP 4096
#define VBIN 4096
#define SLOTS 256
#define NTILE 256
#define CAP2 32768
#define SEGB (NB*HWW/1024)   // 1024 seg blocks (4 px/thread, 256 thr)
#define NMSB (NB*NTILE)      // 512 nms tile blocks
#define STRIP 4096           // k_sums pixels per block
#define ZWORDS (4 + NB*VBIN + NB*(KK+1)*NC + NB*(KK+1))

// NMS tiling
#define TW 128
#define TH 16
#define HALO 3

// ------------- tiny init (hipMemsetAsync costs ~80us in-graph on this system!)
__global__ void __launch_bounds__(256) k_init(uint32_t* zbase) {
    int t = blockIdx.x * 256 + threadIdx.x;
    for (int i = t; i < ZWORDS; i += 32 * 256) zbase[i] = 0u;
}

// ========== fused: per-pixel online-softmax argmax/stat  +  NMS tiles ==========
__global__ void __launch_bounds__(256)
k_seg_nms(const float* __restrict__ logits, const float* __restrict__ cmap,
          float* __restrict__ segs_out, float* __restrict__ scomb,
          unsigned char* __restrict__ seg8,
          uint64_t* __restrict__ cand2, uint32_t* __restrict__ cnt,
          uint32_t* __restrict__ ghist, int use_stats) {
    int bid = blockIdx.x;
    int tid = threadIdx.x;

    if (bid < SEGB) {
        int t = bid * 256 + tid;
        int p = t * 4;
        int b = p / HWW, r = p - b * HWW;
        const float* base = logits + (size_t)b * NC * HWW + r;
        float4 m = make_float4(-3e38f, -3e38f, -3e38f, -3e38f);
        float4 s = make_float4(0.f, 0.f, 0.f, 0.f);
        int ax = 0, ay = 0, az = 0, aw = 0;
#pragma unroll
        for (int c = 0; c < NC; ++c) {
            float4 v = *(const float4*)(base + (size_t)c * HWW);
            if (v.x > m.x) { s.x = s.x * __expf(m.x - v.x) + 1.f; m.x = v.x; ax = c; }
            else            s.x += __expf(v.x - m.x);
            if (v.y > m.y) { s.y = s.y * __expf(m.y - v.y) + 1.f; m.y = v.y; ay = c; }
            else            s.y += __expf(v.y - m.y);
            if (v.z > m.z) { s.z = s.z * __expf(m.z - v.z) + 1.f; m.z = v.z; az = c; }
            else            s.z += __expf(v.z - m.z);
            if (v.w > m.w) { s.w = s.w * __expf(m.w - v.w) + 1.f; m.w = v.w; aw = c; }
            else            s.w += __expf(v.w - m.w);
        }
        *(float4*)(segs_out + p) = make_float4((float)ax, (float)ay, (float)az, (float)aw);
        *(uchar4*)(seg8 + p) = make_uchar4((unsigned char)ax, (unsigned char)ay,
                                           (unsigned char)az, (unsigned char)aw);
        if (use_stats) {   // pr(class c) = exp(logit_c - scomb)
            *(float4*)(scomb + p) = make_float4(m.x + __logf(s.x), m.y + __logf(s.y),
                                                m.z + __logf(s.z), m.w + __logf(s.w));
        }
        return;
    }

    // ---------------- NMS tile: direct dense write + global histogram ----------------
    __shared__ float sIn[TH + 2 * HALO][TW + 2 * HALO];   // 22 x 134
    __shared__ float sH[TH + 2 * HALO][TW];               // 22 x 128
    __shared__ uint64_t lc[SLOTS];
    __shared__ uint32_t lcnt, gbase;
    int t2 = bid - SEGB;
    int bx = t2 & (WW / TW - 1);
    int by = (t2 >> 3) & (HH / TH - 1);
    int b = t2 >> 8;
    const float* bb = cmap + (size_t)b * HWW;
    if (tid == 0) lcnt = 0u;

    const int LW = TW + 2 * HALO;
    const int LH = TH + 2 * HALO;
    for (int idx = tid; idx < LW * LH; idx += 256) {
        int r = idx / LW, c = idx - r * LW;
        int gh = by * TH + r - HALO;
        int gw = bx * TW + c - HALO;
        float v = -3e38f;
        if (gh >= 0 && gh < HH && gw >= 0 && gw < WW) v = bb[gh * WW + gw];
        sIn[r][c] = v;
    }
    __syncthreads();
    for (int idx = tid; idx < LH * TW; idx += 256) {
        int r = idx / TW, c = idx - r * TW;
        float m = fmaxf(fmaxf(fmaxf(sIn[r][c], sIn[r][c + 1]),
                              fmaxf(sIn[r][c + 2], sIn[r][c + 3])),
                        fmaxf(fmaxf(sIn[r][c + 4], sIn[r][c + 5]), sIn[r][c + 6]));
        sH[r][c] = m;
    }
    __syncthreads();
    for (int idx = tid; idx < TH * TW; idx += 256) {
        int r = idx >> 7, c = idx & (TW - 1);
        float cv = sIn[r + HALO][c + HALO];
        float m = fmaxf(fmaxf(fmaxf(sH[r][c], sH[r + 1][c]),
                              fmaxf(sH[r + 2][c], sH[r + 3][c])),
                        fmaxf(fmaxf(sH[r + 4][c], sH[r + 5][c]), sH[r + 6][c]));
        if (m > 0.1f && cv == m) {
            int gh = by * TH + r;
            int gw = bx * TW + c;
            uint32_t rr = (uint32_t)(gh * WW + gw);
            uint32_t pos = atomicAdd(&lcnt, 1u);
            if (pos < SLOTS) {
                lc[pos] = ((uint64_t)__float_as_uint(cv) << 32) |
                          (uint64_t)(0xFFFFFFFFu - rr);
                int bin = (int)(cv * (float)VBIN);
                bin = bin < 0 ? 0 : (bin > VBIN - 1 ? VBIN - 1 : bin);
                atomicAdd(&ghist[b * VBIN + bin], 1u);   // spread bins: low contention
            }
        }
    }
    __syncthreads();
    uint32_t n = lcnt;
    if (n > SLOTS) n = SLOTS;
    if (tid == 0 && n) gbase = atomicAdd(&cnt[b], n);   // ONE global reserve per block
    __syncthreads();
    for (uint32_t i = tid; i < n; i += 256) {
        uint32_t pos = gbase + i;
        if (pos < CAP2) cand2[(size_t)b * CAP2 + pos] = lc[i];
    }
}

// ==== exact top-K from prebuilt hist + dense candidates + exact rank ====
__global__ void __launch_bounds__(1024) k_topk2(const uint64_t* __restrict__ cand2,
                                                const uint32_t* __restrict__ cnt,
                                                const uint32_t* __restrict__ ghist,
                                                float* __restrict__ probs_out,
                                                float* __restrict__ cxy) {
    int b = blockIdx.x;
    int tid = threadIdx.x;
    int lane = tid & 63, wv = tid >> 6;
    __shared__ uint32_t hist[VBIN];
    __shared__ uint32_t part[1024];
    __shared__ uint32_t wsum[16];
    __shared__ uint64_t lkey[MCAP];
    __shared__ uint32_t lM;
    __shared__ int sBstar;

    if (tid < KK) {
        probs_out[b * KK + tid] = 0.f;
        cxy[(b * KK + tid) * 2]     = 1e19f;
        cxy[(b * KK + tid) * 2 + 1] = 1e19f;
    }
    if (tid == 0) { lM = 0u; sBstar = 0; }
    for (int i = tid; i < VBIN; i += 1024) hist[i] = ghist[b * VBIN + i];
    uint32_t N = cnt[b];
    if (N > CAP2) N = CAP2;
    const uint64_t* cb = cand2 + (size_t)b * CAP2;
    __syncthreads();

    // chunk sums in DESCENDING value order, then two-level inclusive scan
    int base = VBIN - 4 * (tid + 1);
    uint32_t s = hist[base] + hist[base + 1] + hist[base + 2] + hist[base + 3];
    uint32_t sc = s;
#pragma unroll
    for (int off = 1; off < 64; off <<= 1) {
        uint32_t nv = __shfl_up(sc, off, 64);
        if (lane >= off) sc += nv;
    }
    if (lane == 63) wsum[wv] = sc;
    __syncthreads();
    if (wv == 0) {
        uint32_t t0 = (lane < 16) ? wsum[lane] : 0u;
#pragma unroll
        for (int off = 1; off < 16; off <<= 1) {
            uint32_t nv = __shfl_up(t0, off, 64);
            if (lane >= off) t0 += nv;
        }
        if (lane < 16) wsum[lane] = t0;
    }
    __syncthreads();
    uint32_t inc = sc + (wv > 0 ? wsum[wv - 1] : 0u);
    part[tid] = inc;
    __syncthreads();
    {
        uint32_t Pt = part[tid];
        uint32_t Pp = (tid > 0) ? part[tid - 1] : 0u;
        if (Pt >= KK && Pp < KK) {
            uint32_t cum = Pp;
            int bs = base;
            for (int j = base + 3; j >= base; --j) {
                cum += hist[j];
                if (cum >= KK) { bs = j; break; }
            }
            sBstar = bs;
        }
    }
    __syncthreads();
    int bstar = sBstar;   // 0 when total candidates <= KK -> collect all

    for (uint32_t i = tid; i < N; i += 1024) {
        uint64_t kk = cb[i];
        float v = __uint_as_float((uint32_t)(kk >> 32));
        int bin = (int)(v * (float)VBIN);
        bin = bin < 0 ? 0 : (bin > VBIN - 1 ? VBIN - 1 : bin);
        if (bin >= bstar) {
            uint32_t pos = atomicAdd(&lM, 1u);
            if (pos < MCAP) lkey[pos] = kk;
        }
    }
    __syncthreads();
    uint32_t M = lM;
    if (M > MCAP) M = MCAP;
    for (uint32_t i = tid; i < M; i += 1024) {
        uint64_t kk = lkey[i];
        uint32_t rank = 0;
        for (uint32_t j = 0; j < M; ++j) rank += (lkey[j] > kk) ? 1u : 0u;
        if (rank < KK) {
            uint32_t bits = (uint32_t)(kk >> 32);
            uint32_t idx = 0xFFFFFFFFu - (uint32_t)(kk & 0xFFFFFFFFull);
            probs_out[b * KK + rank] = __uint_as_float(bits);
            cxy[(b * KK + rank) * 2]     = (float)(idx % WW);
            cxy[(b * KK + rank) * 2 + 1] = (float)(idx / WW);
        }
    }
}

// ------------- closest-center argmin with EXACT per-tile pruning + counts hist
__global__ void __launch_bounds__(256) k_assign(const float* __restrict__ reg,
                                                const float* __restrict__ cxy,
                                                const unsigned char* __restrict__ seg8,
                                                float* __restrict__ closest_out,
                                                uint16_t* __restrict__ aux,
                                                uint32_t* __restrict__ counts) {
    __shared__ float2 cc[KK];
    __shared__ float4 ccs[KK];
    __shared__ float sred[4][4];
    __shared__ uint32_t wcnt[4];
    __shared__ float stau2;
    __shared__ uint32_t sS;

    int t = blockIdx.x;
    int tx = t & 63;
    int ty = (t >> 6) & 31;
    int b = t >> 11;
    int tid = threadIdx.x;
    int lane = tid & 63, wv = tid >> 6;
    int w = tx * 16 + (tid & 15);
    int h = ty * 16 + (tid >> 4);
    int r = h * WW + w;
    int p = b * HWW + r;

    if (tid < KK) cc[tid] = ((const float2*)cxy)[b * KK + tid];
    __syncthreads();

    float rx = reg[(size_t)b * 2 * HWW + r];
    float ry = reg[(size_t)b * 2 * HWW + HWW + r];
    float px = (float)(w + 1) - rx;
    float py = (float)(h + 1) - ry;

    float mnx = px, mxx = px, mny = py, mxy = py;
#pragma unroll
    for (int off = 1; off < 64; off <<= 1) {
        mnx = fminf(mnx, __shfl_xor(mnx, off, 64));
        mxx = fmaxf(mxx, __shfl_xor(mxx, off, 64));
        mny = fminf(mny, __shfl_xor(mny, off, 64));
        mxy = fmaxf(mxy, __shfl_xor(mxy, off, 64));
    }
    if (lane == 0) { sred[0][wv] = mnx; sred[1][wv] = mxx; sred[2][wv] = mny; sred[3][wv] = mxy; }
    __syncthreads();
    float xmin = fminf(fminf(sred[0][0], sred[0][1]), fminf(sred[0][2], sred[0][3]));
    float xmax = fmaxf(fmaxf(sred[1][0], sred[1][1]), fmaxf(sred[1][2], sred[1][3]));
    float ymin = fminf(fminf(sred[2][0], sred[2][1]), fminf(sred[2][2], sred[2][3]));
    float ymax = fmaxf(fmaxf(sred[3][0], sred[3][1]), fmaxf(sred[3][2], sred[3][3]));

    float2 c0 = cc[tid < KK ? tid : 0];
    float mdx = fmaxf(fmaxf(xmin - c0.x, c0.x - xmax), 0.f);
    float mdy = fmaxf(fmaxf(ymin - c0.y, c0.y - ymax), 0.f);
    float mind2 = mdx * mdx + mdy * mdy;
    float Mdx = fmaxf(c0.x - xmin, xmax - c0.x);
    float Mdy = fmaxf(c0.y - ymin, ymax - c0.y);
    float maxd2 = Mdx * Mdx + Mdy * Mdy;

    float v = (tid < KK) ? maxd2 : 3.0e38f;
#pragma unroll
    for (int off = 1; off < 64; off <<= 1) v = fminf(v, __shfl_xor(v, off, 64));
    if (lane == 0) sred[0][wv] = v;
    __syncthreads();
    if (tid == 0) {
        float mm = fminf(fminf(sred[0][0], sred[0][1]), fminf(sred[0][2], sred[0][3]));
        float tau = __builtin_sqrtf(mm) + 1.0f;
        stau2 = tau * tau;
    }
    __syncthreads();

    bool flag = (tid < KK) && (mind2 <= stau2);
    uint64_t mask = __ballot(flag);
    uint32_t myoff = (uint32_t)__popcll(mask & ((1ull << lane) - 1ull));
    if (lane == 0) wcnt[wv] = (uint32_t)__popcll(mask);
    __syncthreads();
    uint32_t pre = 0;
    for (int i = 0; i < wv; ++i) pre += wcnt[i];
    if (flag) ccs[pre + myoff] = make_float4(c0.x, c0.y, (float)tid, 0.f);
    if (tid == 0) sS = wcnt[0] + wcnt[1] + wcnt[2] + wcnt[3];
    __syncthreads();
    uint32_t S = sS;

    float best = __builtin_inff();
    float bkf = 0.f;
    for (uint32_t s = 0; s < S; ++s) {
        float4 c = ccs[s];
        float dx = __fsub_rn(px, c.x);
        float dy = __fsub_rn(py, c.y);
        float d2 = __fadd_rn(__fmul_rn(dx, dx), __fmul_rn(dy, dy));  // no fma, match ref
        if (d2 < best) { best = d2; bkf = c.z; }   // first-occurrence (asc k order)
    }
    int bk = (int)bkf;
    closest_out[p] = bkf + 1.0f;
    int seg = (int)seg8[p];
    aux[p] = (uint16_t)(((bk + 1) << 6) | seg);
    if (seg >= 24 && seg <= 33) {
        atomicAdd(&counts[(b * (KK + 1) + (bk + 1)) * NC + seg], 1u);
    }
}

// ---- per-instance sums over a 4096-px strip; ic recomputed per block from counts
// ---- first strip block of each batch also emits o_ic / o_np / o_va
template <int USE_STATS>
__global__ void __launch_bounds__(256) k_sums(const float* __restrict__ logits,
                                              const uint16_t* __restrict__ aux,
                                              const float* __restrict__ scomb,
                                              const uint32_t* __restrict__ counts,
                                              const float* __restrict__ probs_out,
                                              float* __restrict__ sums,
                                              float* __restrict__ ic_out,
                                              float* __restrict__ np_out,
                                              float* __restrict__ va_out) {
    __shared__ int ic_l[KK];
    __shared__ float psum[KK + 1];
    int tid = threadIdx.x;
    int sblk = blockIdx.x;
    int b = sblk / (HWW / STRIP);
    int p0 = sblk * STRIP;

    if (tid < KK) {   // recompute majority class (identical first-occurrence argmax)
        const uint32_t* row = counts + (size_t)(b * (KK + 1) + (tid + 1)) * NC;
        uint32_t n = 0, mx = 0;
        int am = 0;
#pragma unroll
        for (int c = 0; c < NC; ++c) {
            uint32_t x = row[c];
            n += x;
            if (x > mx) { mx = x; am = c; }
        }
        ic_l[tid] = am;
        if ((sblk % (HWW / STRIP)) == 0) {
            ic_out[b * KK + tid] = (float)am;
            np_out[b * KK + tid] = (float)n;
            va_out[b * KK + tid] =
                (n > 0u && probs_out[b * KK + tid] > 0.f) ? 1.f : 0.f;
        }
    }
    if (tid < KK + 1) psum[tid] = 0.f;
    __syncthreads();

#pragma unroll 1
    for (int ch = 0; ch < STRIP / 512; ++ch) {
        int p = p0 + ch * 512 + tid * 2;
        int r = p - b * HWW;
        uint32_t a2 = *(const uint32_t*)(aux + p);
        int seg0 = (int)(a2 & 63u), seg1 = (int)((a2 >> 16) & 63u);
        bool th0 = (seg0 >= 24) & (seg0 <= 33);
        bool th1 = (seg1 >= 24) & (seg1 <= 33);
        float2 sc = make_float2(0.f, 0.f);
        if (USE_STATS && (th0 || th1)) sc = *(const float2*)(scomb + p);
        const float* base = logits + (size_t)b * NC * HWW + r;
#pragma unroll
        for (int j = 0; j < 2; ++j) {
            bool th = j ? th1 : th0;
            if (th) {
                uint32_t pk = (a2 >> (16 * j)) & 0xFFFFu;
                int cl = (int)(pk >> 6);
                int ic = ic_l[cl - 1];
                float pr;
                if (USE_STATS) {
                    float lv = base[(size_t)ic * HWW + j];
                    pr = __expf(lv - (j ? sc.y : sc.x));
                } else {
                    float vmax = -3e38f, lv = 0.f, s = 0.f;
                    float vv[NC];
#pragma unroll
                    for (int c = 0; c < NC; ++c) {
                        vv[c] = base[(size_t)c * HWW + j];
                        vmax = fmaxf(vmax, vv[c]);
                        if (c == ic) lv = vv[c];
                    }
#pragma unroll
                    for (int c = 0; c < NC; ++c) s += __expf(vv[c] - vmax);
                    pr = __expf(lv - vmax) / s;
                }
                atomicAdd(&psum[cl], pr);
            }
        }
    }
    __syncthreads();
    if (tid < KK + 1) {
        float x = psum[tid];
        if (x != 0.f) atomicAdd(&sums[b * (KK + 1) + tid], x);
    }
}

// ---------------------------------------- final seg_prob
__global__ void __launch_bounds__(256) k_segprob(const float* __restrict__ sums,
                                                 const float* __restrict__ np_out,
                                                 float* __restrict__ sp_out) {
    int t = blockIdx.x * 256 + threadIdx.x;
    if (t >= NB * KK) return;
    int b = t / KK, k = t - b * KK;
    float n = np_out[t];
    float s = sums[b * (KK + 1) + k + 1];
    sp_out[t] = (n > 0.f) ? (s / n) : 0.f;
}

extern "C" void kernel_launch(void* const* d_in, const int* in_sizes, int n_in,
                              void* d_out, int out_size, void* d_ws, size_t ws_size,
                              hipStream_t stream) {
    const float* logits = (const float*)d_in[0];
    const float* cmap   = (const float*)d_in[1];
    const float* reg    = (const float*)d_in[2];
    float* out = (float*)d_out;
    float* o_ic   = out;
    float* o_prob = out + NB * KK;
    float* o_sp   = out + 2 * NB * KK;
    float* o_np   = out + 3 * NB * KK;
    float* o_va   = out + 4 * NB * KK;
    float* o_segs = out + 5 * NB * KK;
    float* o_clo  = out + 5 * NB * KK + NB * HWW;

    char* w = (char*)d_ws;
    size_t off = 0;
    auto alloc = [&](size_t bytes) {
        off = (off + 15) & ~((size_t)15);
        void* p = w + off;
        off += bytes;
        return p;
    };
    uint32_t* zbase  = (uint32_t*)alloc(sizeof(uint32_t) * ZWORDS);
    uint32_t* cnt    = zbase;
    uint32_t* ghist  = zbase + 4;
    uint32_t* counts = ghist + NB * VBIN;
    float*    sums   = (float*)(counts + NB * (KK + 1) * NC);

    uint64_t* cand2  = (uint64_t*)alloc(sizeof(uint64_t) * NB * CAP2);
    float* cxy       = (float*)alloc(sizeof(float) * NB * KK * 2);
    unsigned char* seg8 = (unsigned char*)alloc(sizeof(unsigned char) * NB * HWW);
    uint16_t* aux    = (uint16_t*)alloc(sizeof(uint16_t) * NB * HWW);
    size_t base_need = (off + 15) & ~((size_t)15);
    float* scomb = (float*)(w + base_need);
    int use_stats = (base_need + sizeof(float) * (size_t)NB * HWW) <= ws_size ? 1 : 0;

    k_init<<<32, 256, 0, stream>>>(zbase);
    k_seg_nms<<<SEGB + NMSB, 256, 0, stream>>>(logits, cmap, o_segs, scomb, seg8,
                                               cand2, cnt, ghist, use_stats);
    k_topk2<<<NB, 1024, 0, stream>>>(cand2, cnt, ghist, o_prob, cxy);
    k_assign<<<NB * 2048, 256, 0, stream>>>(reg, cxy, seg8, o_clo, aux, counts);
    if (use_stats)
        k_sums<1><<<NB * HWW / STRIP, 256, 0, stream>>>(logits, aux, scomb, counts,
                                                        o_prob, sums, o_ic, o_np, o_va);
    else
        k_sums<0><<<NB * HWW / STRIP, 256, 0, stream>>>(logits, aux, scomb, counts,
                                                        o_prob, sums, o_ic, o_np, o_va);
    k_segprob<<<(NB * KK + 255) / 256, 256, 0, stream>>>(sums, o_np, o_sp);
}

// Round 14
// 101.811 us; speedup vs baseline: 1.1118x; 1.0895x over previous
//
#include <hip/hip_runtime.h>
#include <stdint.h>

#define NB 2
#define NC 34
#define HH 512
#define WW 1024
#define HWW (HH*WW)
#define KK 200
#define MCAP 4096
#define VBIN 4096
#define SLOTS 256
#define NTILE 256
#define SEGB (NB*HWW/1024)   // 1024 seg blocks (4 px/thread, 256 thr)
#define NMSB (NB*NTILE)      // 512 nms tile blocks
#define STRIP 4096           // k_sums pixels per block
#define SUMB (NB*HWW/STRIP)  // 256 k_sums blocks

// NMS tiling
#define TW 128
#define TH 16
#define HALO 3

// ========== fused: per-pixel online-softmax argmax/stat  +  NMS tiles ==========
__global__ void __launch_bounds__(256)
k_seg_nms(const float* __restrict__ logits, const float* __restrict__ cmap,
          float* __restrict__ segs_out, float* __restrict__ scomb,
          unsigned char* __restrict__ seg8,
          uint64_t* __restrict__ cand, uint32_t* __restrict__ tcnt,
          int use_stats) {
    int bid = blockIdx.x;
    int tid = threadIdx.x;

    if (bid < SEGB) {
        int t = bid * 256 + tid;
        int p = t * 4;
        int b = p / HWW, r = p - b * HWW;
        const float* base = logits + (size_t)b * NC * HWW + r;
        float4 m = make_float4(-3e38f, -3e38f, -3e38f, -3e38f);
        float4 s = make_float4(0.f, 0.f, 0.f, 0.f);
        int ax = 0, ay = 0, az = 0, aw = 0;
#pragma unroll
        for (int c = 0; c < NC; ++c) {
            float4 v = *(const float4*)(base + (size_t)c * HWW);
            if (v.x > m.x) { s.x = s.x * __expf(m.x - v.x) + 1.f; m.x = v.x; ax = c; }
            else            s.x += __expf(v.x - m.x);
            if (v.y > m.y) { s.y = s.y * __expf(m.y - v.y) + 1.f; m.y = v.y; ay = c; }
            else            s.y += __expf(v.y - m.y);
            if (v.z > m.z) { s.z = s.z * __expf(m.z - v.z) + 1.f; m.z = v.z; az = c; }
            else            s.z += __expf(v.z - m.z);
            if (v.w > m.w) { s.w = s.w * __expf(m.w - v.w) + 1.f; m.w = v.w; aw = c; }
            else            s.w += __expf(v.w - m.w);
        }
        *(float4*)(segs_out + p) = make_float4((float)ax, (float)ay, (float)az, (float)aw);
        *(uchar4*)(seg8 + p) = make_uchar4((unsigned char)ax, (unsigned char)ay,
                                           (unsigned char)az, (unsigned char)aw);
        if (use_stats) {   // pr(class c) = exp(logit_c - scomb)
            *(float4*)(scomb + p) = make_float4(m.x + __logf(s.x), m.y + __logf(s.y),
                                                m.z + __logf(s.z), m.w + __logf(s.w));
        }
        return;
    }

    // ------------- NMS tile: per-tile slots + unconditional tcnt (no init needed)
    __shared__ float sIn[TH + 2 * HALO][TW + 2 * HALO];   // 22 x 134
    __shared__ float sH[TH + 2 * HALO][TW];               // 22 x 128
    __shared__ uint64_t lc[SLOTS];
    __shared__ uint32_t lcnt;
    int t2 = bid - SEGB;
    int bx = t2 & (WW / TW - 1);
    int by = (t2 >> 3) & (HH / TH - 1);
    int b = t2 >> 8;
    int tb = t2 & (NTILE - 1);
    const float* bb = cmap + (size_t)b * HWW;
    if (tid == 0) lcnt = 0u;

    const int LW = TW + 2 * HALO;
    const int LH = TH + 2 * HALO;
    for (int idx = tid; idx < LW * LH; idx += 256) {
        int r = idx / LW, c = idx - r * LW;
        int gh = by * TH + r - HALO;
        int gw = bx * TW + c - HALO;
        float v = -3e38f;
        if (gh >= 0 && gh < HH && gw >= 0 && gw < WW) v = bb[gh * WW + gw];
        sIn[r][c] = v;
    }
    __syncthreads();
    for (int idx = tid; idx < LH * TW; idx += 256) {
        int r = idx / TW, c = idx - r * TW;
        float m = fmaxf(fmaxf(fmaxf(sIn[r][c], sIn[r][c + 1]),
                              fmaxf(sIn[r][c + 2], sIn[r][c + 3])),
                        fmaxf(fmaxf(sIn[r][c + 4], sIn[r][c + 5]), sIn[r][c + 6]));
        sH[r][c] = m;
    }
    __syncthreads();
    for (int idx = tid; idx < TH * TW; idx += 256) {
        int r = idx >> 7, c = idx & (TW - 1);
        float cv = sIn[r + HALO][c + HALO];
        float m = fmaxf(fmaxf(fmaxf(sH[r][c], sH[r + 1][c]),
                              fmaxf(sH[r + 2][c], sH[r + 3][c])),
                        fmaxf(fmaxf(sH[r + 4][c], sH[r + 5][c]), sH[r + 6][c]));
        if (m > 0.1f && cv == m) {
            int gh = by * TH + r;
            int gw = bx * TW + c;
            uint32_t rr = (uint32_t)(gh * WW + gw);
            uint32_t pos = atomicAdd(&lcnt, 1u);
            if (pos < SLOTS)
                lc[pos] = ((uint64_t)__float_as_uint(cv) << 32) |
                          (uint64_t)(0xFFFFFFFFu - rr);
        }
    }
    __syncthreads();
    uint32_t n = lcnt;
    if (n > SLOTS) n = SLOTS;
    uint64_t* cslot = cand + ((size_t)(b * NTILE + tb)) * SLOTS;
    for (uint32_t i = tid; i < n; i += 256) cslot[i] = lc[i];
    if (tid == 0) tcnt[b * NTILE + tb] = n;   // written every call: no init needed
}

// ==== exact top-K from tiled slots (guarded gather) + zero ws for later stages ====
__global__ void __launch_bounds__(1024) k_topk2(const uint64_t* __restrict__ cand,
                                                const uint32_t* __restrict__ tcnt,
                                                float* __restrict__ probs_out,
                                                float* __restrict__ cxy,
                                                uint32_t* __restrict__ counts,
                                                float* __restrict__ sums,
                                                uint32_t* __restrict__ done) {
    int b = blockIdx.x;
    int tid = threadIdx.x;
    int lane = tid & 63, wv = tid >> 6;
    __shared__ uint32_t hist[VBIN];
    __shared__ uint32_t part[1024];
    __shared__ uint32_t wsum[16];
    __shared__ uint32_t ltc[NTILE];
    __shared__ uint64_t lkey[MCAP];
    __shared__ uint32_t lM;
    __shared__ int sBstar;

    // zero ws consumed by LATER dispatches (k_assign / k_sums): safe, ordered
    {
        uint32_t* zc = counts + (size_t)b * (KK + 1) * NC;
        for (int i = tid; i < (KK + 1) * NC; i += 1024) zc[i] = 0u;
        float* zs = sums + b * (KK + 1);
        for (int i = tid; i < KK + 1; i += 1024) zs[i] = 0.f;
        if (b == 0 && tid == 0) done[0] = 0u;
    }
    if (tid < KK) {
        probs_out[b * KK + tid] = 0.f;
        cxy[(b * KK + tid) * 2]     = 1e19f;
        cxy[(b * KK + tid) * 2 + 1] = 1e19f;
    }
    if (tid == 0) { lM = 0u; sBstar = 0; }
    if (tid < NTILE) ltc[tid] = tcnt[b * NTILE + tid];
    for (int i = tid; i < VBIN; i += 1024) hist[i] = 0u;
    __syncthreads();

    const uint64_t* cb = cand + (size_t)b * NTILE * SLOTS;
    int tile = tid >> 2, l4 = tid & 3;   // 4 threads per tile
    uint32_t n_t = ltc[tile];

    // pass A: value-binned histogram over all valid slots
    for (uint32_t sl = l4; sl < n_t; sl += 4) {
        uint64_t kk = cb[tile * SLOTS + sl];
        float v = __uint_as_float((uint32_t)(kk >> 32));
        int bin = (int)(v * (float)VBIN);
        bin = bin < 0 ? 0 : (bin > VBIN - 1 ? VBIN - 1 : bin);
        atomicAdd(&hist[bin], 1u);
    }
    __syncthreads();

    // chunk sums in DESCENDING value order, then two-level inclusive scan
    int base = VBIN - 4 * (tid + 1);
    uint32_t s = hist[base] + hist[base + 1] + hist[base + 2] + hist[base + 3];
    uint32_t sc = s;
#pragma unroll
    for (int off = 1; off < 64; off <<= 1) {
        uint32_t nv = __shfl_up(sc, off, 64);
        if (lane >= off) sc += nv;
    }
    if (lane == 63) wsum[wv] = sc;
    __syncthreads();
    if (wv == 0) {
        uint32_t t0 = (lane < 16) ? wsum[lane] : 0u;
#pragma unroll
        for (int off = 1; off < 16; off <<= 1) {
            uint32_t nv = __shfl_up(t0, off, 64);
            if (lane >= off) t0 += nv;
        }
        if (lane < 16) wsum[lane] = t0;
    }
    __syncthreads();
    uint32_t inc = sc + (wv > 0 ? wsum[wv - 1] : 0u);
    part[tid] = inc;
    __syncthreads();
    {
        uint32_t Pt = part[tid];
        uint32_t Pp = (tid > 0) ? part[tid - 1] : 0u;
        if (Pt >= KK && Pp < KK) {
            uint32_t cum = Pp;
            int bs = base;
            for (int j = base + 3; j >= base; --j) {
                cum += hist[j];
                if (cum >= KK) { bs = j; break; }
            }
            sBstar = bs;
        }
    }
    __syncthreads();
    int bstar = sBstar;   // 0 when total candidates <= KK -> collect all

    // pass B: collect keys with bin >= bstar
    for (uint32_t sl = l4; sl < n_t; sl += 4) {
        uint64_t kk = cb[tile * SLOTS + sl];
        float v = __uint_as_float((uint32_t)(kk >> 32));
        int bin = (int)(v * (float)VBIN);
        bin = bin < 0 ? 0 : (bin > VBIN - 1 ? VBIN - 1 : bin);
        if (bin >= bstar) {
            uint32_t pos = atomicAdd(&lM, 1u);
            if (pos < MCAP) lkey[pos] = kk;
        }
    }
    __syncthreads();
    uint32_t M = lM;
    if (M > MCAP) M = MCAP;
    // exact global rank (desc value, asc index via ~idx in low bits)
    for (uint32_t i = tid; i < M; i += 1024) {
        uint64_t kk = lkey[i];
        uint32_t rank = 0;
        for (uint32_t j = 0; j < M; ++j) rank += (lkey[j] > kk) ? 1u : 0u;
        if (rank < KK) {
            uint32_t bits = (uint32_t)(kk >> 32);
            uint32_t idx = 0xFFFFFFFFu - (uint32_t)(kk & 0xFFFFFFFFull);
            probs_out[b * KK + rank] = __uint_as_float(bits);
            cxy[(b * KK + rank) * 2]     = (float)(idx % WW);
            cxy[(b * KK + rank) * 2 + 1] = (float)(idx / WW);
        }
    }
}

// ------------- closest-center argmin with EXACT per-tile pruning + counts hist
__global__ void __launch_bounds__(256) k_assign(const float* __restrict__ reg,
                                                const float* __restrict__ cxy,
                                                const unsigned char* __restrict__ seg8,
                                                float* __restrict__ closest_out,
                                                uint16_t* __restrict__ aux,
                                                uint32_t* __restrict__ counts) {
    __shared__ float2 cc[KK];
    __shared__ float4 ccs[KK];
    __shared__ float sred[4][4];
    __shared__ uint32_t wcnt[4];
    __shared__ float stau2;
    __shared__ uint32_t sS;

    int t = blockIdx.x;
    int tx = t & 63;
    int ty = (t >> 6) & 31;
    int b = t >> 11;
    int tid = threadIdx.x;
    int lane = tid & 63, wv = tid >> 6;
    int w = tx * 16 + (tid & 15);
    int h = ty * 16 + (tid >> 4);
    int r = h * WW + w;
    int p = b * HWW + r;

    if (tid < KK) cc[tid] = ((const float2*)cxy)[b * KK + tid];
    __syncthreads();

    float rx = reg[(size_t)b * 2 * HWW + r];
    float ry = reg[(size_t)b * 2 * HWW + HWW + r];
    float px = (float)(w + 1) - rx;
    float py = (float)(h + 1) - ry;

    float mnx = px, mxx = px, mny = py, mxy = py;
#pragma unroll
    for (int off = 1; off < 64; off <<= 1) {
        mnx = fminf(mnx, __shfl_xor(mnx, off, 64));
        mxx = fmaxf(mxx, __shfl_xor(mxx, off, 64));
        mny = fminf(mny, __shfl_xor(mny, off, 64));
        mxy = fmaxf(mxy, __shfl_xor(mxy, off, 64));
    }
    if (lane == 0) { sred[0][wv] = mnx; sred[1][wv] = mxx; sred[2][wv] = mny; sred[3][wv] = mxy; }
    __syncthreads();
    float xmin = fminf(fminf(sred[0][0], sred[0][1]), fminf(sred[0][2], sred[0][3]));
    float xmax = fmaxf(fmaxf(sred[1][0], sred[1][1]), fmaxf(sred[1][2], sred[1][3]));
    float ymin = fminf(fminf(sred[2][0], sred[2][1]), fminf(sred[2][2], sred[2][3]));
    float ymax = fmaxf(fmaxf(sred[3][0], sred[3][1]), fmaxf(sred[3][2], sred[3][3]));

    float2 c0 = cc[tid < KK ? tid : 0];
    float mdx = fmaxf(fmaxf(xmin - c0.x, c0.x - xmax), 0.f);
    float mdy = fmaxf(fmaxf(ymin - c0.y, c0.y - ymax), 0.f);
    float mind2 = mdx * mdx + mdy * mdy;
    float Mdx = fmaxf(c0.x - xmin, xmax - c0.x);
    float Mdy = fmaxf(c0.y - ymin, ymax - c0.y);
    float maxd2 = Mdx * Mdx + Mdy * Mdy;

    float v = (tid < KK) ? maxd2 : 3.0e38f;
#pragma unroll
    for (int off = 1; off < 64; off <<= 1) v = fminf(v, __shfl_xor(v, off, 64));
    if (lane == 0) sred[0][wv] = v;
    __syncthreads();
    if (tid == 0) {
        float mm = fminf(fminf(sred[0][0], sred[0][1]), fminf(sred[0][2], sred[0][3]));
        float tau = __builtin_sqrtf(mm) + 1.0f;
        stau2 = tau * tau;
    }
    __syncthreads();

    bool flag = (tid < KK) && (mind2 <= stau2);
    uint64_t mask = __ballot(flag);
    uint32_t myoff = (uint32_t)__popcll(mask & ((1ull << lane) - 1ull));
    if (lane == 0) wcnt[wv] = (uint32_t)__popcll(mask);
    __syncthreads();
    uint32_t pre = 0;
    for (int i = 0; i < wv; ++i) pre += wcnt[i];
    if (flag) ccs[pre + myoff] = make_float4(c0.x, c0.y, (float)tid, 0.f);
    if (tid == 0) sS = wcnt[0] + wcnt[1] + wcnt[2] + wcnt[3];
    __syncthreads();
    uint32_t S = sS;

    float best = __builtin_inff();
    float bkf = 0.f;
    for (uint32_t s = 0; s < S; ++s) {
        float4 c = ccs[s];
        float dx = __fsub_rn(px, c.x);
        float dy = __fsub_rn(py, c.y);
        float d2 = __fadd_rn(__fmul_rn(dx, dx), __fmul_rn(dy, dy));  // no fma, match ref
        if (d2 < best) { best = d2; bkf = c.z; }   // first-occurrence (asc k order)
    }
    int bk = (int)bkf;
    closest_out[p] = bkf + 1.0f;
    int seg = (int)seg8[p];
    aux[p] = (uint16_t)(((bk + 1) << 6) | seg);
    if (seg >= 24 && seg <= 33) {
        atomicAdd(&counts[(b * (KK + 1) + (bk + 1)) * NC + seg], 1u);
    }
}

// ---- per-instance sums over a 4096-px strip; ic recomputed per block from counts
// ---- first strip block per batch emits o_ic/o_np/o_va; LAST block (ticket) does seg_prob
template <int USE_STATS>
__global__ void __launch_bounds__(256) k_sums(const float* __restrict__ logits,
                                              const uint16_t* __restrict__ aux,
                                              const float* __restrict__ scomb,
                                              const uint32_t* __restrict__ counts,
                                              const float* __restrict__ probs_out,
                                              float* __restrict__ sums,
                                              float* __restrict__ ic_out,
                                              float* __restrict__ np_out,
                                              float* __restrict__ va_out,
                                              float* __restrict__ sp_out,
                                              uint32_t* __restrict__ done) {
    __shared__ int ic_l[KK];
    __shared__ float psum[KK + 1];
    __shared__ uint32_t sticket;
    int tid = threadIdx.x;
    int sblk = blockIdx.x;
    int b = sblk / (HWW / STRIP);
    int p0 = sblk * STRIP;

    if (tid < KK) {   // recompute majority class (identical first-occurrence argmax)
        const uint32_t* row = counts + (size_t)(b * (KK + 1) + (tid + 1)) * NC;
        uint32_t n = 0, mx = 0;
        int am = 0;
#pragma unroll
        for (int c = 0; c < NC; ++c) {
            uint32_t x = row[c];
            n += x;
            if (x > mx) { mx = x; am = c; }
        }
        ic_l[tid] = am;
        if ((sblk % (HWW / STRIP)) == 0) {
            ic_out[b * KK + tid] = (float)am;
            np_out[b * KK + tid] = (float)n;
            va_out[b * KK + tid] =
                (n > 0u && probs_out[b * KK + tid] > 0.f) ? 1.f : 0.f;
        }
    }
    if (tid < KK + 1) psum[tid] = 0.f;
    __syncthreads();

#pragma unroll 1
    for (int ch = 0; ch < STRIP / 512; ++ch) {
        int p = p0 + ch * 512 + tid * 2;
        int r = p - b * HWW;
        uint32_t a2 = *(const uint32_t*)(aux + p);
        int seg0 = (int)(a2 & 63u), seg1 = (int)((a2 >> 16) & 63u);
        bool th0 = (seg0 >= 24) & (seg0 <= 33);
        bool th1 = (seg1 >= 24) & (seg1 <= 33);
        float2 sc = make_float2(0.f, 0.f);
        if (USE_STATS && (th0 || th1)) sc = *(const float2*)(scomb + p);
        const float* base = logits + (size_t)b * NC * HWW + r;
#pragma unroll
        for (int j = 0; j < 2; ++j) {
            bool th = j ? th1 : th0;
            if (th) {
                uint32_t pk = (a2 >> (16 * j)) & 0xFFFFu;
                int cl = (int)(pk >> 6);
                int ic = ic_l[cl - 1];
                float pr;
                if (USE_STATS) {
                    float lv = base[(size_t)ic * HWW + j];
                    pr = __expf(lv - (j ? sc.y : sc.x));
                } else {
                    float vmax = -3e38f, lv = 0.f, s = 0.f;
                    float vv[NC];
#pragma unroll
                    for (int c = 0; c < NC; ++c) {
                        vv[c] = base[(size_t)c * HWW + j];
                        vmax = fmaxf(vmax, vv[c]);
                        if (c == ic) lv = vv[c];
                    }
#pragma unroll
                    for (int c = 0; c < NC; ++c) s += __expf(vv[c] - vmax);
                    pr = __expf(lv - vmax) / s;
                }
                atomicAdd(&psum[cl], pr);
            }
        }
    }
    __syncthreads();
    if (tid < KK + 1) {
        float x = psum[tid];
        if (x != 0.f) atomicAdd(&sums[b * (KK + 1) + tid], x);
    }
    // ---- seg_prob in the LAST block (256-block ticket: ~3.6us, saves a dispatch)
    __threadfence();
    __syncthreads();
    if (tid == 0) sticket = atomicAdd(&done[0], 1u);
    __syncthreads();
    if (sticket == (uint32_t)SUMB - 1u) {
        __threadfence();
        for (int t = tid; t < NB * KK; t += 256) {
            int bb = t / KK, k = t - bb * KK;
            const uint32_t* row = counts + (size_t)(bb * (KK + 1) + (k + 1)) * NC;
            uint32_t n = 0;
#pragma unroll
            for (int c = 0; c < NC; ++c) n += row[c];
            float s2 = atomicAdd(&sums[bb * (KK + 1) + k + 1], 0.f);  // coherent read
            sp_out[t] = (n > 0u) ? (s2 / (float)n) : 0.f;
        }
    }
}

extern "C" void kernel_launch(void* const* d_in, const int* in_sizes, int n_in,
                              void* d_out, int out_size, void* d_ws, size_t ws_size,
                              hipStream_t stream) {
    const float* logits = (const float*)d_in[0];
    const float* cmap   = (const float*)d_in[1];
    const float* reg    = (const float*)d_in[2];
    float* out = (float*)d_out;
    float* o_ic   = out;
    float* o_prob = out + NB * KK;
    float* o_sp   = out + 2 * NB * KK;
    float* o_np   = out + 3 * NB * KK;
    float* o_va   = out + 4 * NB * KK;
    float* o_segs = out + 5 * NB * KK;
    float* o_clo  = out + 5 * NB * KK + NB * HWW;

    char* w = (char*)d_ws;
    size_t off = 0;
    auto alloc = [&](size_t bytes) {
        off = (off + 15) & ~((size_t)15);
        void* p = w + off;
        off += bytes;
        return p;
    };
    uint64_t* cand   = (uint64_t*)alloc(sizeof(uint64_t) * NB * NTILE * SLOTS);
    uint32_t* tcnt   = (uint32_t*)alloc(sizeof(uint32_t) * NB * NTILE);
    uint32_t* counts = (uint32_t*)alloc(sizeof(uint32_t) * NB * (KK + 1) * NC);
    float* sums      = (float*)alloc(sizeof(float) * NB * (KK + 1));
    uint32_t* done   = (uint32_t*)alloc(sizeof(uint32_t) * 4);
    float* cxy       = (float*)alloc(sizeof(float) * NB * KK * 2);
    unsigned char* seg8 = (unsigned char*)alloc(sizeof(unsigned char) * NB * HWW);
    uint16_t* aux    = (uint16_t*)alloc(sizeof(uint16_t) * NB * HWW);
    size_t base_need = (off + 15) & ~((size_t)15);
    float* scomb = (float*)(w + base_need);
    int use_stats = (base_need + sizeof(float) * (size_t)NB * HWW) <= ws_size ? 1 : 0;

    k_seg_nms<<<SEGB + NMSB, 256, 0, stream>>>(logits, cmap, o_segs, scomb, seg8,
                                               cand, tcnt, use_stats);
    k_topk2<<<NB, 1024, 0, stream>>>(cand, tcnt, o_prob, cxy, counts, sums, done);
    k_assign<<<NB * 2048, 256, 0, stream>>>(reg, cxy, seg8, o_clo, aux, counts);
    if (use_stats)
        k_sums<1><<<SUMB, 256, 0, stream>>>(logits, aux, scomb, counts, o_prob,
                                            sums, o_ic, o_np, o_va, o_sp, done);
    else
        k_sums<0><<<SUMB, 256, 0, stream>>>(logits, aux, scomb, counts, o_prob,
                                            sums, o_ic, o_np, o_va, o_sp, done);
}